// Round 13
// baseline (569.024 us; speedup 1.0000x reference)
//
#include <hip/hip_runtime.h>
#include <hip/hip_bf16.h>
#include <math.h>

#define GAMMA 0.1f
#define EPSILON 0.1f
#define NUM_ITERS 4
#define BSHIFT 9           // bucket covers 512 dst nodes
#define CH_P 36
#define CH_SZ (16 * CH_P)   // 576 floats per buffer

typedef __attribute__((ext_vector_type(8))) short short8;   // 8 bf16 bit-patterns
typedef __attribute__((ext_vector_type(4))) float floatx4;
typedef __attribute__((ext_vector_type(2))) float floatx2;

__device__ __forceinline__ float bf2f(unsigned short u) {
  union { unsigned int i; float f; } v; v.i = ((unsigned int)u) << 16; return v.f;
}
__device__ __forceinline__ unsigned short f2bf(float f) {
  union { float f; unsigned int i; } v; v.f = f;
  unsigned int x = v.i;
  return (unsigned short)((x + 0x7fffu + ((x >> 16) & 1u)) >> 16);
}
__device__ __forceinline__ unsigned int f2_to_bfx2(float a, float b) {
  return (unsigned int)f2bf(a) | (((unsigned int)f2bf(b)) << 16);
}
__device__ __forceinline__ float2 bfx2_to_f2(unsigned int u) {
  union { unsigned int i; float f; } lo, hi;
  lo.i = u << 16; hi.i = u & 0xffff0000u;
  return make_float2(lo.f, hi.f);
}
__device__ __forceinline__ float tanh_fast(float s) {
  float c = fminf(15.0f, fmaxf(-15.0f, s));
  float e = __expf(2.0f * c);
  return (e - 1.0f) * __frcp_rn(e + 1.0f);
}

// ---------------- fp8 (OCP e4m3) pack/unpack, HW cvt with SW fallback --------

#if defined(__has_builtin)
#if __has_builtin(__builtin_amdgcn_cvt_pk_f32_fp8) && __has_builtin(__builtin_amdgcn_cvt_pk_fp8_f32)
#define FP8_HW 1
#endif
#endif

__device__ __forceinline__ float e4m3_to_f_sw(unsigned int b) {
  unsigned int s = (b >> 7) & 1u, e = (b >> 3) & 15u, m = b & 7u;
  float v;
  if (e) { union { unsigned int u; float f; } c; c.u = ((e + 120u) << 23) | (m << 20); v = c.f; }
  else v = (float)m * 0.001953125f;   // m * 2^-9
  return s ? -v : v;
}
__device__ __forceinline__ unsigned int f_to_e4m3_sw(float x) {
  union { float f; unsigned int u; } v; v.f = x;
  unsigned int sgn = (v.u >> 24) & 0x80u;
  float a = fabsf(x);
  if (a < 0.0009765625f) return sgn;             // below half min-denormal -> 0
  if (a > 448.f) return sgn | 0x7Eu;             // saturate to 448
  v.f = a;
  int e32 = (int)((v.u >> 23) & 0xffu) - 127;
  if (e32 < -6) {                                 // denormal
    int q = (int)(a * 512.0f + 0.5f);
    if (q > 7) q = 7;
    return sgn | (unsigned)q;
  }
  unsigned int u = v.u + 0x000FFFFFu + ((v.u >> 20) & 1u);  // RNE to 3 mantissa bits
  int e = (int)((u >> 23) & 0xffu) - 127;
  if (e > 8) return sgn | 0x7Eu;
  unsigned int m = (u >> 20) & 7u;
  return sgn | ((unsigned)(e + 7) << 3) | m;
}

// decode 2 fp8 (low/high 16-bit word of w) -> packed floatx2 (feeds v_pk_add_f32)
__device__ __forceinline__ floatx2 fp8x2_cvt_lo(unsigned int w) {
#ifdef FP8_HW
  return __builtin_amdgcn_cvt_pk_f32_fp8(w, false);
#else
  floatx2 r; r.x = e4m3_to_f_sw(w & 0xffu); r.y = e4m3_to_f_sw((w >> 8) & 0xffu); return r;
#endif
}
__device__ __forceinline__ floatx2 fp8x2_cvt_hi(unsigned int w) {
#ifdef FP8_HW
  return __builtin_amdgcn_cvt_pk_f32_fp8(w, true);
#else
  floatx2 r; r.x = e4m3_to_f_sw((w >> 16) & 0xffu); r.y = e4m3_to_f_sw((w >> 24) & 0xffu); return r;
#endif
}
// pack 4 f32 -> 4 fp8 in one dword
__device__ __forceinline__ unsigned int fp8x4_enc(float a, float b, float c, float d) {
#ifdef FP8_HW
  unsigned int w = (unsigned int)__builtin_amdgcn_cvt_pk_fp8_f32(a, b, 0, false);
  w = (unsigned int)__builtin_amdgcn_cvt_pk_fp8_f32(c, d, (int)w, true);
  return w;
#else
  return f_to_e4m3_sw(a) | (f_to_e4m3_sw(b) << 8) | (f_to_e4m3_sw(c) << 16) | (f_to_e4m3_sw(d) << 24);
#endif
}

// ------------------------------------------------------------- dtype detect

__global__ void detect_kernel(const unsigned int* __restrict__ x, int* __restrict__ flag) {
  __shared__ int ws4[4];
  int tid = threadIdx.x;
  int bad = 0;
  for (int i = tid; i < 2048; i += 256) {
    unsigned int u = x[i];
    float lo = bf2f((unsigned short)(u & 0xffffu));
    if (!(fabsf(lo) <= 64.0f)) bad++;
  }
#pragma unroll
  for (int d = 1; d < 64; d <<= 1) bad += __shfl_xor(bad, d, 64);
  if ((tid & 63) == 0) ws4[tid >> 6] = bad;
  __syncthreads();
  if (tid == 0) *flag = (ws4[0] + ws4[1] + ws4[2] + ws4[3] > 64) ? 1 : 0;
}

// ------------------------------------------------------------- setup

__global__ void fill_kernel(unsigned short* __restrict__ out, int n, unsigned short val) {
  int t = blockIdx.x * blockDim.x + threadIdx.x;
  if (t < n) out[t] = val;
}

__global__ void prep_kernel(const void* __restrict__ Wv, const void* __restrict__ Wphiv,
                            const void* __restrict__ biasv, const int* __restrict__ flag,
                            unsigned short* __restrict__ Am, unsigned short* __restrict__ Wb,
                            float* __restrict__ bias_f) {
  int t = blockIdx.x * blockDim.x + threadIdx.x;
  if (t >= 128 * 128) return;
  int isf = *flag;
  int j = t >> 7, k = t & 127;
  float w_jk, w_kj, wp;
  if (isf) {
    const float* W = (const float*)Wv;
    const float* Wp = (const float*)Wphiv;
    w_jk = W[t]; w_kj = W[k * 128 + j]; wp = Wp[t];
  } else {
    const unsigned short* W = (const unsigned short*)Wv;
    const unsigned short* Wp = (const unsigned short*)Wphiv;
    w_jk = bf2f(W[t]); w_kj = bf2f(W[k * 128 + j]); wp = bf2f(Wp[t]);
  }
  float v = w_jk - w_kj;
  if (j == k) v -= GAMMA;
  Am[t] = f2bf(v);
  Wb[t] = f2bf(wp);
  if (t < 128)
    bias_f[t] = isf ? ((const float*)biasv)[t] : bf2f(((const unsigned short*)biasv)[t]);
}

// xb <- bf16(x_in), pad rows zero. One thread per 8 elements.
__global__ void init_x_kernel(const void* __restrict__ xinv, const int* __restrict__ flag,
                              unsigned short* __restrict__ xb, int N, int NP) {
  int t = blockIdx.x * blockDim.x + threadIdx.x;
  if (t >= NP * 16) return;
  int base = t * 8;
  int row = base >> 7;
  uint4 o;
  if (row < N) {
    if (*flag) {
      const float* p = (const float*)xinv + base;
      float4 f0 = *(const float4*)p;
      float4 f1 = *(const float4*)(p + 4);
      o.x = f2_to_bfx2(f0.x, f0.y); o.y = f2_to_bfx2(f0.z, f0.w);
      o.z = f2_to_bfx2(f1.x, f1.y); o.w = f2_to_bfx2(f1.z, f1.w);
    } else {
      o = *(const uint4*)((const unsigned short*)xinv + base);
    }
  } else {
    o = make_uint4(0u, 0u, 0u, 0u);
  }
  *(uint4*)(xb + base) = o;
}

// z(fp8) <- e4m3( dinv[row] * xb )
__global__ void scale_kernel(const unsigned short* __restrict__ xb,
                             const float* __restrict__ dinv,
                             unsigned char* __restrict__ zf, int NP16) {
  int t = blockIdx.x * blockDim.x + threadIdx.x;
  if (t >= NP16) return;
  int base = t * 8;
  float dv = dinv[base >> 7];
  uint4 u = *(const uint4*)(xb + base);
  float2 f0 = bfx2_to_f2(u.x), f1 = bfx2_to_f2(u.y);
  float2 f2 = bfx2_to_f2(u.z), f3 = bfx2_to_f2(u.w);
  uint2 o;
  o.x = fp8x4_enc(f0.x * dv, f0.y * dv, f1.x * dv, f1.y * dv);
  o.y = fp8x4_enc(f2.x * dv, f2.y * dv, f3.x * dv, f3.y * dv);
  *(uint2*)(zf + base) = o;
}

// -------------------- bucketed CSR build --------------
// bpairs packed: (dstLocal << 23) | src  -- dstLocal < 512 (9b), src < 2^23

__global__ void bcount_kernel(const int* __restrict__ dst, int* __restrict__ gcnt,
                              int E, int NB) {
  __shared__ int cnt[512];
  int tid = threadIdx.x;
  for (int j = tid; j < 512; j += 256) cnt[j] = 0;
  __syncthreads();
  int base = blockIdx.x * 4096;
#pragma unroll
  for (int k = 0; k < 16; ++k) {
    int i = base + k * 256 + tid;
    if (i < E) atomicAdd(&cnt[dst[i] >> BSHIFT], 1);
  }
  __syncthreads();
  for (int j = tid; j < NB; j += 256)
    if (cnt[j]) atomicAdd(&gcnt[j], cnt[j]);
}

// parallel exclusive scan over NB buckets (one 256-thread block)
__global__ void bscan_kernel(const int* __restrict__ gcnt, int* __restrict__ gofs,
                             int* __restrict__ gcur, int NB, int E) {
  if (NB <= 256) {
    __shared__ int wsum[4];
    int t = threadIdx.x;
    int v = (t < NB) ? gcnt[t] : 0;
    int lane = t & 63, w = t >> 6;
    int inc = v;
#pragma unroll
    for (int d = 1; d < 64; d <<= 1) { int q = __shfl_up(inc, d, 64); if (lane >= d) inc += q; }
    if (lane == 63) wsum[w] = inc;
    __syncthreads();
    int woff = 0;
    for (int k = 0; k < w; ++k) woff += wsum[k];
    int ex = woff + inc - v;     // exclusive prefix
    if (t < NB) { gofs[t] = ex; gcur[t] = ex; }
    if (t == 0) gofs[NB] = E;
  } else if (threadIdx.x == 0) {
    int run = 0;
    for (int i = 0; i < NB; ++i) { gofs[i] = run; gcur[i] = run; run += gcnt[i]; }
    gofs[NB] = E;
  }
}

__global__ void bscatter_kernel(const int* __restrict__ src, const int* __restrict__ dst,
                                int* __restrict__ gcur, unsigned int* __restrict__ bpairs,
                                int E, int NB) {
  __shared__ int cnt[512];
  __shared__ int pos[512];
  int tid = threadIdx.x;
  for (int j = tid; j < 512; j += 256) cnt[j] = 0;
  __syncthreads();
  int base = blockIdx.x * 4096;
#pragma unroll
  for (int k = 0; k < 16; ++k) {
    int i = base + k * 256 + tid;
    if (i < E) atomicAdd(&cnt[dst[i] >> BSHIFT], 1);
  }
  __syncthreads();
  for (int j = tid; j < NB; j += 256)
    pos[j] = cnt[j] ? atomicAdd(&gcur[j], cnt[j]) : 0;
  __syncthreads();
#pragma unroll
  for (int k = 0; k < 16; ++k) {
    int i = base + k * 256 + tid;
    if (i < E) {
      int d = dst[i];
      int slot = atomicAdd(&pos[d >> BSHIFT], 1);
      bpairs[slot] = (((unsigned)d & 511u) << 23) | (unsigned)src[i];
    }
  }
}

__global__ __launch_bounds__(256) void bfinal_kernel(
    const unsigned int* __restrict__ bpairs, const int* __restrict__ gofs,
    int* __restrict__ offs, float* __restrict__ dinv, int* __restrict__ csr,
    int N, int NP, int E) {
  __shared__ int dl[512];
  __shared__ int cur[512];
  __shared__ int wsum2[4];
  int b = blockIdx.x, t = threadIdx.x;
  int node0 = b << BSHIFT;
  dl[t] = 0; dl[t + 256] = 0;
  __syncthreads();
  int e0 = gofs[b], e1 = gofs[b + 1];
  for (int i = e0 + t; i < e1; i += 256)
    atomicAdd(&dl[bpairs[i] >> 23], 1);
  __syncthreads();
  int v0 = dl[2 * t], v1 = dl[2 * t + 1];
  int ps = v0 + v1;
  int lane = t & 63, w = t >> 6;
  int inc = ps;
#pragma unroll
  for (int d = 1; d < 64; d <<= 1) { int q = __shfl_up(inc, d, 64); if (lane >= d) inc += q; }
  if (lane == 63) wsum2[w] = inc;
  __syncthreads();
  int woff = 0;
  for (int k = 0; k < w; ++k) woff += wsum2[k];
  int base = e0 + woff + inc - ps;
  int n0 = node0 + 2 * t, n1 = node0 + 2 * t + 1;
  if (n0 < N) offs[n0] = base;
  if (n1 < N) offs[n1] = base + v0;
  if (n0 < NP) dinv[n0] = rsqrtf((float)v0 + 1.0f);
  if (n1 < NP) dinv[n1] = rsqrtf((float)v1 + 1.0f);
  cur[2 * t] = base;
  cur[2 * t + 1] = base + v0;
  if (b == 0 && t == 0) offs[N] = E;
  __syncthreads();
  for (int i = e0 + t; i < e1; i += 256) {
    unsigned int p = bpairs[i];
    int s = atomicAdd(&cur[p >> 23], 1);
    csr[s] = (int)(p & 0x7FFFFFu);
  }
}

// ------------------------------------------------------------- per-iteration

// fused update, 2 tiles (128 rows) per block:
//   stage Am once -> GEMM1(tileA)+GEMM1(tileB) -> stage Wphi once ->
//   GEMM2(A)+GEMM2(B) -> bar -> epilogue(A), epilogue(B) (per-wave scratch,
//   no barrier between tiles). Halves staging traffic+barriers and eliminates
//   the dispatch tail (782 blocks, all co-resident at >=3 blocks/CU).
//   Epilogue re-reads x from xb (L2-hot) instead of carrying afrag across
//   tiles, keeping VGPR in the 4-waves/SIMD range. Accumulation order per
//   tile is identical to the 1-tile version -> numerics unchanged.
#define DO_GEMM(ACC, ROWBASE, SRC) { \
    const int arow_ = (ROWBASE) + wid * 16 + l15; \
    const size_t ab_ = (size_t)arow_ * 128 + quad * 8; \
    short8 fr_[4]; \
    _Pragma("unroll") \
    for (int kk = 0; kk < 4; ++kk) fr_[kk] = *(const short8*)((SRC) + ab_ + kk * 32); \
    _Pragma("unroll") \
    for (int kk = 0; kk < 4; ++kk) { \
      _Pragma("unroll") \
      for (int j = 0; j < 8; ++j) { \
        short8 b_ = *(const short8*)(bsm + (j * 16 + l15) * 128 + (((kk * 4 + quad) ^ rsw) * 8)); \
        ACC[j] = __builtin_amdgcn_mfma_f32_16x16x32_bf16(fr_[kk], b_, ACC[j], 0, 0, 0); \
      } \
    } \
  }

#define DO_EPI(ACC, ROWBASE) { \
    const int arow_ = (ROWBASE) + wid * 16 + l15; \
    const size_t ab_ = (size_t)arow_ * 128 + quad * 8; \
    const float dva_ = dinv[arow_]; \
    const bool valid_ = arow_ < Mvalid; \
    float* wbuf_ = (float*)bsm + wid * 2 * CH_SZ; \
    _Pragma("unroll") \
    for (int kk = 0; kk < 4; ++kk) { \
      float* buf_ = wbuf_ + (kk & 1) * CH_SZ; \
      _Pragma("unroll") \
      for (int jj = 0; jj < 2; ++jj) { \
        _Pragma("unroll") \
        for (int r = 0; r < 4; ++r) \
          buf_[(quad * 4 + r) * CH_P + jj * 16 + l15] = ACC[2 * kk + jj][r]; \
      } \
      const int col0_ = kk * 32 + quad * 8; \
      const float* ap_ = &buf_[l15 * CH_P + quad * 8]; \
      float4 s0_ = *(const float4*)ap_; \
      float4 s1_ = *(const float4*)(ap_ + 4); \
      float4 b0_ = *(const float4*)&bias_f[col0_]; \
      float4 b1_ = *(const float4*)&bias_f[col0_ + 4]; \
      uint4 xw_ = *(const uint4*)(xb + ab_ + kk * 32); \
      float2 x01_ = bfx2_to_f2(xw_.x), x23_ = bfx2_to_f2(xw_.y); \
      float2 x45_ = bfx2_to_f2(xw_.z), x67_ = bfx2_to_f2(xw_.w); \
      float xv_[8]; \
      xv_[0] = x01_.x + EPSILON * tanh_fast(s0_.x + b0_.x); \
      xv_[1] = x01_.y + EPSILON * tanh_fast(s0_.y + b0_.y); \
      xv_[2] = x23_.x + EPSILON * tanh_fast(s0_.z + b0_.z); \
      xv_[3] = x23_.y + EPSILON * tanh_fast(s0_.w + b0_.w); \
      xv_[4] = x45_.x + EPSILON * tanh_fast(s1_.x + b1_.x); \
      xv_[5] = x45_.y + EPSILON * tanh_fast(s1_.y + b1_.y); \
      xv_[6] = x67_.x + EPSILON * tanh_fast(s1_.z + b1_.z); \
      xv_[7] = x67_.y + EPSILON * tanh_fast(s1_.w + b1_.w); \
      uint4 pk_; \
      pk_.x = f2_to_bfx2(xv_[0], xv_[1]); pk_.y = f2_to_bfx2(xv_[2], xv_[3]); \
      pk_.z = f2_to_bfx2(xv_[4], xv_[5]); pk_.w = f2_to_bfx2(xv_[6], xv_[7]); \
      if (valid_) { \
        *(uint4*)(xb + ab_ + kk * 32) = pk_; \
        if (znext) { \
          uint2 zk_; \
          zk_.x = fp8x4_enc(xv_[0] * dva_, xv_[1] * dva_, xv_[2] * dva_, xv_[3] * dva_); \
          zk_.y = fp8x4_enc(xv_[4] * dva_, xv_[5] * dva_, xv_[6] * dva_, xv_[7] * dva_); \
          *(uint2*)(znext + ab_ + kk * 32) = zk_; \
        } \
        if (outb) { \
          if (isf) { \
            float* op_ = (float*)outb + ab_ + kk * 32; \
            *(float4*)op_ = make_float4(xv_[0], xv_[1], xv_[2], xv_[3]); \
            *(float4*)(op_ + 4) = make_float4(xv_[4], xv_[5], xv_[6], xv_[7]); \
          } else { \
            *(uint4*)((unsigned short*)outb + ab_ + kk * 32) = pk_; \
          } \
        } \
      } \
    } \
  }

__global__ __launch_bounds__(256) void fused_kernel(
    unsigned short* __restrict__ xb, const unsigned short* __restrict__ Am,
    const unsigned short* __restrict__ Wphi, const float* __restrict__ dinv,
    const unsigned short* __restrict__ g, const float* __restrict__ bias_f,
    void* __restrict__ outb, unsigned char* __restrict__ znext,
    const int* __restrict__ flag, int Mvalid, int ntiles) {
  __shared__ __align__(16) unsigned short bsm[128 * 128];   // 32768 B
  const int tid = threadIdx.x, lane = tid & 63, wid = tid >> 6;
  const int l15 = lane & 15, quad = lane >> 4;
  const int t0 = blockIdx.x * 2;
  const bool hasB = (t0 + 1) < ntiles;
  const int rsw = (l15 & 7);
  const int isf = *flag;

  // ---- stage Am into LDS (swizzled), coalesced 16B per thread x 8
#pragma unroll
  for (int p = 0; p < 8; ++p) {
    int c = p * 256 + tid;               // 16B-chunk index, 0..2047
    int row = c >> 4, slot = c & 15;
    *(uint4*)(bsm + row * 128 + ((slot ^ (row & 7)) * 8)) = *(const uint4*)(Am + c * 8);
  }
  __syncthreads();

  floatx4 accA[8], accB[8];
  const floatx4 zero = {0.f, 0.f, 0.f, 0.f};
#pragma unroll
  for (int j = 0; j < 8; ++j) { accA[j] = zero; accB[j] = zero; }

  DO_GEMM(accA, t0 * 64, xb);
  if (hasB) DO_GEMM(accB, (t0 + 1) * 64, xb);
  __syncthreads();

  // ---- stage Wphi over the same region
#pragma unroll
  for (int p = 0; p < 8; ++p) {
    int c = p * 256 + tid;
    int row = c >> 4, slot = c & 15;
    *(uint4*)(bsm + row * 128 + ((slot ^ (row & 7)) * 8)) = *(const uint4*)(Wphi + c * 8);
  }
  __syncthreads();

  DO_GEMM(accA, t0 * 64, g);
  if (hasB) DO_GEMM(accB, (t0 + 1) * 64, g);
  __syncthreads();   // all B reads done; bsm now reusable as transpose scratch

  DO_EPI(accA, t0 * 64);          // per-wave scratch; same-wave ordering only
  if (hasB) DO_EPI(accB, (t0 + 1) * 64);
}

// one wave per node, quad-per-edge gather over fp8 z rows (128 B/row, 8 B/lane)
// accumulators are packed floatx2 -> v_pk_add_f32 (R9 version: measured 52-53 us,
// at the L1/TA random-gather line-rate floor)
__global__ __launch_bounds__(256) void agg_kernel(
    const unsigned char* __restrict__ zf,
    const int* __restrict__ offs,
    const int* __restrict__ csr,
    const float* __restrict__ dinv,
    unsigned short* __restrict__ g,
    int N) {
  int i = blockIdx.x * 4 + (threadIdx.x >> 6);
  if (i >= N) return;
  int lane = threadIdx.x & 63;
  int sub = lane >> 4;
  int c8 = (lane & 15) * 8;    // byte offset (8 fp8 elems per lane)

  floatx2 a01 = {0.f, 0.f}, a23 = {0.f, 0.f}, a45 = {0.f, 0.f}, a67 = {0.f, 0.f};

#define ACC8F(u) { \
  a01 += fp8x2_cvt_lo((u).x); \
  a23 += fp8x2_cvt_hi((u).x); \
  a45 += fp8x2_cvt_lo((u).y); \
  a67 += fp8x2_cvt_hi((u).y); }

  int e0 = offs[i], e1 = offs[i + 1];
  int e = e0 + sub;
  for (; e + 4 < e1; e += 8) {
    int s0 = csr[e];
    int s1 = csr[e + 4];
    uint2 u0 = *(const uint2*)(zf + (size_t)s0 * 128 + c8);
    uint2 u1 = *(const uint2*)(zf + (size_t)s1 * 128 + c8);
    ACC8F(u0); ACC8F(u1);
  }
  if (e < e1) {
    int s0 = csr[e];
    uint2 u0 = *(const uint2*)(zf + (size_t)s0 * 128 + c8);
    ACC8F(u0);
  }

  float a0 = a01.x, a1 = a01.y, a2 = a23.x, a3 = a23.y;
  float a4 = a45.x, a5 = a45.y, a6 = a67.x, a7 = a67.y;

  a0 += __shfl_xor(a0, 16, 64); a0 += __shfl_xor(a0, 32, 64);
  a1 += __shfl_xor(a1, 16, 64); a1 += __shfl_xor(a1, 32, 64);
  a2 += __shfl_xor(a2, 16, 64); a2 += __shfl_xor(a2, 32, 64);
  a3 += __shfl_xor(a3, 16, 64); a3 += __shfl_xor(a3, 32, 64);
  a4 += __shfl_xor(a4, 16, 64); a4 += __shfl_xor(a4, 32, 64);
  a5 += __shfl_xor(a5, 16, 64); a5 += __shfl_xor(a5, 32, 64);
  a6 += __shfl_xor(a6, 16, 64); a6 += __shfl_xor(a6, 32, 64);
  a7 += __shfl_xor(a7, 16, 64); a7 += __shfl_xor(a7, 32, 64);

  if (sub == 0) {
    uint2 su = *(const uint2*)(zf + (size_t)i * 128 + c8);
    floatx2 s01 = fp8x2_cvt_lo(su.x), s23 = fp8x2_cvt_hi(su.x);
    floatx2 s45 = fp8x2_cvt_lo(su.y), s67 = fp8x2_cvt_hi(su.y);
    a0 += s01.x; a1 += s01.y; a2 += s23.x; a3 += s23.y;
    a4 += s45.x; a5 += s45.y; a6 += s67.x; a7 += s67.y;
    float dv = dinv[i];
    uint4 o;
    o.x = f2_to_bfx2(a0 * dv, a1 * dv);
    o.y = f2_to_bfx2(a2 * dv, a3 * dv);
    o.z = f2_to_bfx2(a4 * dv, a5 * dv);
    o.w = f2_to_bfx2(a6 * dv, a7 * dv);
    *(uint4*)(g + (size_t)i * 128 + c8) = o;   // g is bf16: c8 = ushort index here
  }
#undef ACC8F
}

// ------------------------------------------------------------- launch

extern "C" void kernel_launch(void* const* d_in, const int* in_sizes, int n_in,
                              void* d_out, int out_size, void* d_ws, size_t ws_size,
                              hipStream_t stream) {
  const void* x_in = d_in[0];
  const int* ei = (const int*)d_in[1];
  const void* W = d_in[2];
  const void* Wphi = d_in[3];
  const void* bias = d_in[4];

  const int N = in_sizes[0] / 128;
  const int E = in_sizes[1] / 2;
  const int NP = ((N + 63) / 64) * 64;
  const int* src = ei;
  const int* dst = ei + E;
  const int NB = (N + 511) >> BSHIFT;
  const int EB = (E + 4095) / 4096;

  size_t off = 0;
  auto place = [&](size_t bytes) { size_t r = off; off = (off + bytes + 255) & ~(size_t)255; return r; };
  size_t o_xb   = place((size_t)NP * 128 * 2);
  size_t o_z    = place((size_t)NP * 128);       // fp8: 1 B/elem
  size_t o_g    = place((size_t)NP * 128 * 2);
  size_t o_Am   = place(128 * 128 * 2);
  size_t o_Wb   = place(128 * 128 * 2);
  size_t o_bf   = place(128 * 4);
  size_t o_flag = place(4);
  size_t o_dinv = place((size_t)(NB * 512 + 64) * 4);
  size_t o_offs = place((size_t)(N + 1) * 4);
  size_t o_gcnt = place((size_t)NB * 4);
  size_t o_gofs = place((size_t)(NB + 1) * 4);
  size_t o_gcur = place((size_t)NB * 4);
  size_t o_bprs = place((size_t)E * 4);          // packed uint32 per edge
  size_t o_csr  = place((size_t)E * 4);
  if (off > ws_size || in_sizes[0] % 128 != 0 || out_size != N * 128 || n_in < 5 ||
      N > (1 << 23)) {
    fill_kernel<<<(out_size * 2 + 255) / 256, 256, 0, stream>>>(
        (unsigned short*)d_out, out_size, (unsigned short)0x3F80);
    return;
  }
  char* basep = (char*)d_ws;
  unsigned short* xb = (unsigned short*)(basep + o_xb);
  unsigned char* zf  = (unsigned char*)(basep + o_z);
  unsigned short* g  = (unsigned short*)(basep + o_g);
  unsigned short* Am = (unsigned short*)(basep + o_Am);
  unsigned short* Wb = (unsigned short*)(basep + o_Wb);
  float* bias_f = (float*)(basep + o_bf);
  int* flag   = (int*)(basep + o_flag);
  float* dinv = (float*)(basep + o_dinv);
  int* offs   = (int*)(basep + o_offs);
  int* gcnt   = (int*)(basep + o_gcnt);
  int* gofs   = (int*)(basep + o_gofs);
  int* gcur   = (int*)(basep + o_gcur);
  unsigned int* bpairs = (unsigned int*)(basep + o_bprs);
  int* csr    = (int*)(basep + o_csr);

  hipMemsetAsync(gcnt, 0, (size_t)NB * 4, stream);
  detect_kernel<<<1, 256, 0, stream>>>((const unsigned int*)x_in, flag);
  prep_kernel<<<(128 * 128 + 255) / 256, 256, 0, stream>>>(W, Wphi, bias, flag, Am, Wb, bias_f);
  init_x_kernel<<<(NP * 16 + 255) / 256, 256, 0, stream>>>(x_in, flag, xb, N, NP);
  bcount_kernel<<<EB, 256, 0, stream>>>(dst, gcnt, E, NB);
  bscan_kernel<<<1, 256, 0, stream>>>(gcnt, gofs, gcur, NB, E);
  bscatter_kernel<<<EB, 256, 0, stream>>>(src, dst, gcur, bpairs, E, NB);
  bfinal_kernel<<<NB, 256, 0, stream>>>(bpairs, gofs, offs, dinv, csr, N, NP, E);

  const int ntiles = NP / 64;
  const int gblocks = (ntiles + 1) / 2;
  scale_kernel<<<(NP * 16 + 255) / 256, 256, 0, stream>>>(xb, dinv, zf, NP * 16);
  for (int t = 0; t < NUM_ITERS; ++t) {
    agg_kernel<<<(N + 3) / 4, 256, 0, stream>>>(zf, offs, csr, dinv, g, N);
    void* outp = (t == NUM_ITERS - 1) ? d_out : nullptr;
    unsigned char* znext = (t == NUM_ITERS - 1) ? nullptr : zf;
    fused_kernel<<<gblocks, 256, 0, stream>>>(xb, Am, Wb, dinv, g, bias_f,
                                              outp, znext, flag, N, ntiles);
  }
}

// Round 14
// 490.121 us; speedup vs baseline: 1.1610x; 1.1610x over previous
//
#include <hip/hip_runtime.h>
#include <hip/hip_bf16.h>
#include <math.h>

#define GAMMA 0.1f
#define EPSILON 0.1f
#define NUM_ITERS 4
#define BSHIFT 9           // bucket covers 512 dst nodes
#define CH_P 36
#define CH_SZ (16 * CH_P)   // 576 floats per buffer

typedef __attribute__((ext_vector_type(8))) short short8;   // 8 bf16 bit-patterns
typedef __attribute__((ext_vector_type(4))) float floatx4;
typedef __attribute__((ext_vector_type(2))) float floatx2;

__device__ __forceinline__ float bf2f(unsigned short u) {
  union { unsigned int i; float f; } v; v.i = ((unsigned int)u) << 16; return v.f;
}
__device__ __forceinline__ unsigned short f2bf(float f) {
  union { float f; unsigned int i; } v; v.f = f;
  unsigned int x = v.i;
  return (unsigned short)((x + 0x7fffu + ((x >> 16) & 1u)) >> 16);
}
__device__ __forceinline__ unsigned int f2_to_bfx2(float a, float b) {
  return (unsigned int)f2bf(a) | (((unsigned int)f2bf(b)) << 16);
}
__device__ __forceinline__ float2 bfx2_to_f2(unsigned int u) {
  union { unsigned int i; float f; } lo, hi;
  lo.i = u << 16; hi.i = u & 0xffff0000u;
  return make_float2(lo.f, hi.f);
}
__device__ __forceinline__ float tanh_fast(float s) {
  float c = fminf(15.0f, fmaxf(-15.0f, s));
  float e = __expf(2.0f * c);
  return (e - 1.0f) * __frcp_rn(e + 1.0f);
}

// ---------------- fp8 (OCP e4m3) pack/unpack, HW cvt with SW fallback --------

#if defined(__has_builtin)
#if __has_builtin(__builtin_amdgcn_cvt_pk_f32_fp8) && __has_builtin(__builtin_amdgcn_cvt_pk_fp8_f32)
#define FP8_HW 1
#endif
#endif

__device__ __forceinline__ float e4m3_to_f_sw(unsigned int b) {
  unsigned int s = (b >> 7) & 1u, e = (b >> 3) & 15u, m = b & 7u;
  float v;
  if (e) { union { unsigned int u; float f; } c; c.u = ((e + 120u) << 23) | (m << 20); v = c.f; }
  else v = (float)m * 0.001953125f;   // m * 2^-9
  return s ? -v : v;
}
__device__ __forceinline__ unsigned int f_to_e4m3_sw(float x) {
  union { float f; unsigned int u; } v; v.f = x;
  unsigned int sgn = (v.u >> 24) & 0x80u;
  float a = fabsf(x);
  if (a < 0.0009765625f) return sgn;             // below half min-denormal -> 0
  if (a > 448.f) return sgn | 0x7Eu;             // saturate to 448
  v.f = a;
  int e32 = (int)((v.u >> 23) & 0xffu) - 127;
  if (e32 < -6) {                                 // denormal
    int q = (int)(a * 512.0f + 0.5f);
    if (q > 7) q = 7;
    return sgn | (unsigned)q;
  }
  unsigned int u = v.u + 0x000FFFFFu + ((v.u >> 20) & 1u);  // RNE to 3 mantissa bits
  int e = (int)((u >> 23) & 0xffu) - 127;
  if (e > 8) return sgn | 0x7Eu;
  unsigned int m = (u >> 20) & 7u;
  return sgn | ((unsigned)(e + 7) << 3) | m;
}

// decode 2 fp8 (low/high 16-bit word of w) -> packed floatx2 (feeds v_pk_add_f32)
__device__ __forceinline__ floatx2 fp8x2_cvt_lo(unsigned int w) {
#ifdef FP8_HW
  return __builtin_amdgcn_cvt_pk_f32_fp8(w, false);
#else
  floatx2 r; r.x = e4m3_to_f_sw(w & 0xffu); r.y = e4m3_to_f_sw((w >> 8) & 0xffu); return r;
#endif
}
__device__ __forceinline__ floatx2 fp8x2_cvt_hi(unsigned int w) {
#ifdef FP8_HW
  return __builtin_amdgcn_cvt_pk_f32_fp8(w, true);
#else
  floatx2 r; r.x = e4m3_to_f_sw((w >> 16) & 0xffu); r.y = e4m3_to_f_sw((w >> 24) & 0xffu); return r;
#endif
}
// pack 4 f32 -> 4 fp8 in one dword
__device__ __forceinline__ unsigned int fp8x4_enc(float a, float b, float c, float d) {
#ifdef FP8_HW
  unsigned int w = (unsigned int)__builtin_amdgcn_cvt_pk_fp8_f32(a, b, 0, false);
  w = (unsigned int)__builtin_amdgcn_cvt_pk_fp8_f32(c, d, (int)w, true);
  return w;
#else
  return f_to_e4m3_sw(a) | (f_to_e4m3_sw(b) << 8) | (f_to_e4m3_sw(c) << 16) | (f_to_e4m3_sw(d) << 24);
#endif
}

// ------------------------------------------------------------- dtype detect

__global__ void detect_kernel(const unsigned int* __restrict__ x, int* __restrict__ flag) {
  __shared__ int ws4[4];
  int tid = threadIdx.x;
  int bad = 0;
  for (int i = tid; i < 2048; i += 256) {
    unsigned int u = x[i];
    float lo = bf2f((unsigned short)(u & 0xffffu));
    if (!(fabsf(lo) <= 64.0f)) bad++;
  }
#pragma unroll
  for (int d = 1; d < 64; d <<= 1) bad += __shfl_xor(bad, d, 64);
  if ((tid & 63) == 0) ws4[tid >> 6] = bad;
  __syncthreads();
  if (tid == 0) *flag = (ws4[0] + ws4[1] + ws4[2] + ws4[3] > 64) ? 1 : 0;
}

// ------------------------------------------------------------- setup

__global__ void fill_kernel(unsigned short* __restrict__ out, int n, unsigned short val) {
  int t = blockIdx.x * blockDim.x + threadIdx.x;
  if (t < n) out[t] = val;
}

__global__ void prep_kernel(const void* __restrict__ Wv, const void* __restrict__ Wphiv,
                            const void* __restrict__ biasv, const int* __restrict__ flag,
                            unsigned short* __restrict__ Am, unsigned short* __restrict__ Wb,
                            float* __restrict__ bias_f) {
  int t = blockIdx.x * blockDim.x + threadIdx.x;
  if (t >= 128 * 128) return;
  int isf = *flag;
  int j = t >> 7, k = t & 127;
  float w_jk, w_kj, wp;
  if (isf) {
    const float* W = (const float*)Wv;
    const float* Wp = (const float*)Wphiv;
    w_jk = W[t]; w_kj = W[k * 128 + j]; wp = Wp[t];
  } else {
    const unsigned short* W = (const unsigned short*)Wv;
    const unsigned short* Wp = (const unsigned short*)Wphiv;
    w_jk = bf2f(W[t]); w_kj = bf2f(W[k * 128 + j]); wp = bf2f(Wp[t]);
  }
  float v = w_jk - w_kj;
  if (j == k) v -= GAMMA;
  Am[t] = f2bf(v);
  Wb[t] = f2bf(wp);
  if (t < 128)
    bias_f[t] = isf ? ((const float*)biasv)[t] : bf2f(((const unsigned short*)biasv)[t]);
}

// xb <- bf16(x_in), pad rows zero. One thread per 8 elements.
__global__ void init_x_kernel(const void* __restrict__ xinv, const int* __restrict__ flag,
                              unsigned short* __restrict__ xb, int N, int NP) {
  int t = blockIdx.x * blockDim.x + threadIdx.x;
  if (t >= NP * 16) return;
  int base = t * 8;
  int row = base >> 7;
  uint4 o;
  if (row < N) {
    if (*flag) {
      const float* p = (const float*)xinv + base;
      float4 f0 = *(const float4*)p;
      float4 f1 = *(const float4*)(p + 4);
      o.x = f2_to_bfx2(f0.x, f0.y); o.y = f2_to_bfx2(f0.z, f0.w);
      o.z = f2_to_bfx2(f1.x, f1.y); o.w = f2_to_bfx2(f1.z, f1.w);
    } else {
      o = *(const uint4*)((const unsigned short*)xinv + base);
    }
  } else {
    o = make_uint4(0u, 0u, 0u, 0u);
  }
  *(uint4*)(xb + base) = o;
}

// z(fp8) <- e4m3( dinv[row] * xb )
__global__ void scale_kernel(const unsigned short* __restrict__ xb,
                             const float* __restrict__ dinv,
                             unsigned char* __restrict__ zf, int NP16) {
  int t = blockIdx.x * blockDim.x + threadIdx.x;
  if (t >= NP16) return;
  int base = t * 8;
  float dv = dinv[base >> 7];
  uint4 u = *(const uint4*)(xb + base);
  float2 f0 = bfx2_to_f2(u.x), f1 = bfx2_to_f2(u.y);
  float2 f2 = bfx2_to_f2(u.z), f3 = bfx2_to_f2(u.w);
  uint2 o;
  o.x = fp8x4_enc(f0.x * dv, f0.y * dv, f1.x * dv, f1.y * dv);
  o.y = fp8x4_enc(f2.x * dv, f2.y * dv, f3.x * dv, f3.y * dv);
  *(uint2*)(zf + base) = o;
}

// -------------------- bucketed CSR build --------------
// bpairs packed: (dstLocal << 23) | src  -- dstLocal < 512 (9b), src < 2^23

__global__ void bcount_kernel(const int* __restrict__ dst, int* __restrict__ gcnt,
                              int E, int NB) {
  __shared__ int cnt[512];
  int tid = threadIdx.x;
  for (int j = tid; j < 512; j += 256) cnt[j] = 0;
  __syncthreads();
  int base = blockIdx.x * 4096;
#pragma unroll
  for (int k = 0; k < 16; ++k) {
    int i = base + k * 256 + tid;
    if (i < E) atomicAdd(&cnt[dst[i] >> BSHIFT], 1);
  }
  __syncthreads();
  for (int j = tid; j < NB; j += 256)
    if (cnt[j]) atomicAdd(&gcnt[j], cnt[j]);
}

// parallel exclusive scan over NB buckets (one 256-thread block)
__global__ void bscan_kernel(const int* __restrict__ gcnt, int* __restrict__ gofs,
                             int* __restrict__ gcur, int NB, int E) {
  if (NB <= 256) {
    __shared__ int wsum[4];
    int t = threadIdx.x;
    int v = (t < NB) ? gcnt[t] : 0;
    int lane = t & 63, w = t >> 6;
    int inc = v;
#pragma unroll
    for (int d = 1; d < 64; d <<= 1) { int q = __shfl_up(inc, d, 64); if (lane >= d) inc += q; }
    if (lane == 63) wsum[w] = inc;
    __syncthreads();
    int woff = 0;
    for (int k = 0; k < w; ++k) woff += wsum[k];
    int ex = woff + inc - v;     // exclusive prefix
    if (t < NB) { gofs[t] = ex; gcur[t] = ex; }
    if (t == 0) gofs[NB] = E;
  } else if (threadIdx.x == 0) {
    int run = 0;
    for (int i = 0; i < NB; ++i) { gofs[i] = run; gcur[i] = run; run += gcnt[i]; }
    gofs[NB] = E;
  }
}

__global__ void bscatter_kernel(const int* __restrict__ src, const int* __restrict__ dst,
                                int* __restrict__ gcur, unsigned int* __restrict__ bpairs,
                                int E, int NB) {
  __shared__ int cnt[512];
  __shared__ int pos[512];
  int tid = threadIdx.x;
  for (int j = tid; j < 512; j += 256) cnt[j] = 0;
  __syncthreads();
  int base = blockIdx.x * 4096;
#pragma unroll
  for (int k = 0; k < 16; ++k) {
    int i = base + k * 256 + tid;
    if (i < E) atomicAdd(&cnt[dst[i] >> BSHIFT], 1);
  }
  __syncthreads();
  for (int j = tid; j < NB; j += 256)
    pos[j] = cnt[j] ? atomicAdd(&gcur[j], cnt[j]) : 0;
  __syncthreads();
#pragma unroll
  for (int k = 0; k < 16; ++k) {
    int i = base + k * 256 + tid;
    if (i < E) {
      int d = dst[i];
      int slot = atomicAdd(&pos[d >> BSHIFT], 1);
      bpairs[slot] = (((unsigned)d & 511u) << 23) | (unsigned)src[i];
    }
  }
}

__global__ __launch_bounds__(256) void bfinal_kernel(
    const unsigned int* __restrict__ bpairs, const int* __restrict__ gofs,
    int* __restrict__ offs, float* __restrict__ dinv, int* __restrict__ csr,
    int N, int NP, int E) {
  __shared__ int dl[512];
  __shared__ int cur[512];
  __shared__ int wsum2[4];
  int b = blockIdx.x, t = threadIdx.x;
  int node0 = b << BSHIFT;
  dl[t] = 0; dl[t + 256] = 0;
  __syncthreads();
  int e0 = gofs[b], e1 = gofs[b + 1];
  for (int i = e0 + t; i < e1; i += 256)
    atomicAdd(&dl[bpairs[i] >> 23], 1);
  __syncthreads();
  int v0 = dl[2 * t], v1 = dl[2 * t + 1];
  int ps = v0 + v1;
  int lane = t & 63, w = t >> 6;
  int inc = ps;
#pragma unroll
  for (int d = 1; d < 64; d <<= 1) { int q = __shfl_up(inc, d, 64); if (lane >= d) inc += q; }
  if (lane == 63) wsum2[w] = inc;
  __syncthreads();
  int woff = 0;
  for (int k = 0; k < w; ++k) woff += wsum2[k];
  int base = e0 + woff + inc - ps;
  int n0 = node0 + 2 * t, n1 = node0 + 2 * t + 1;
  if (n0 < N) offs[n0] = base;
  if (n1 < N) offs[n1] = base + v0;
  if (n0 < NP) dinv[n0] = rsqrtf((float)v0 + 1.0f);
  if (n1 < NP) dinv[n1] = rsqrtf((float)v1 + 1.0f);
  cur[2 * t] = base;
  cur[2 * t + 1] = base + v0;
  if (b == 0 && t == 0) offs[N] = E;
  __syncthreads();
  for (int i = e0 + t; i < e1; i += 256) {
    unsigned int p = bpairs[i];
    int s = atomicAdd(&cur[p >> 23], 1);
    csr[s] = (int)(p & 0x7FFFFFu);
  }
}

// ------------------------------------------------------------- per-iteration

// fused update (bf16 state, fp8 z-output) — R12 structure (1 tile/block,
// VGPR 64, 5 blocks/CU; 2-tile variant regressed via spills, R13):
//   Phase-split LDS-staged GEMMs (32 KB region, XOR-swizzled):
//     stage Am -> bar -> acc += x@Am^T -> bar -> stage Wphi -> bar ->
//     acc += s@Wphi^T -> bar -> reuse region as per-wave transpose scratch.
//   epilogue: h = tanh(acc + bias); x' = x + eps*h; store xb (skipped on the
//   final iteration: outb carries the result and nothing reads xb after),
//   znext = e4m3(dinv*x'), optional out.
__global__ __launch_bounds__(256) void fused_kernel(
    unsigned short* __restrict__ xb, const unsigned short* __restrict__ Am,
    const unsigned short* __restrict__ Wphi, const float* __restrict__ dinv,
    const unsigned short* __restrict__ g, const float* __restrict__ bias_f,
    void* __restrict__ outb, unsigned char* __restrict__ znext,
    const int* __restrict__ flag, int Mvalid) {
  __shared__ __align__(16) unsigned short bsm[128 * 128];   // 32768 B
  const int tid = threadIdx.x, lane = tid & 63, wid = tid >> 6;
  const int l15 = lane & 15, quad = lane >> 4;
  const int m0 = blockIdx.x * 64;
  const int arow = m0 + wid * 16 + l15;
  const size_t abase = (size_t)arow * 128 + quad * 8;

  short8 afrag[4], sfrag[4];
#pragma unroll
  for (int kk = 0; kk < 4; ++kk) afrag[kk] = *(const short8*)(xb + abase + kk * 32);
#pragma unroll
  for (int kk = 0; kk < 4; ++kk) sfrag[kk] = *(const short8*)(g + abase + kk * 32);
  const float dva = dinv[arow];

  // ---- stage Am into LDS (swizzled), coalesced 16B per thread x 8
#pragma unroll
  for (int p = 0; p < 8; ++p) {
    int c = p * 256 + tid;               // 16B-chunk index, 0..2047
    int row = c >> 4, slot = c & 15;
    *(uint4*)(bsm + row * 128 + ((slot ^ (row & 7)) * 8)) = *(const uint4*)(Am + c * 8);
  }
  __syncthreads();

  floatx4 acc[8];
  const floatx4 zero = {0.f, 0.f, 0.f, 0.f};
#pragma unroll
  for (int j = 0; j < 8; ++j) acc[j] = zero;
  const int rsw = (l15 & 7);             // row&7 for all B rows this lane reads
#pragma unroll
  for (int kk = 0; kk < 4; ++kk) {
#pragma unroll
    for (int j = 0; j < 8; ++j) {
      short8 b = *(const short8*)(bsm + (j * 16 + l15) * 128 + (((kk * 4 + quad) ^ rsw) * 8));
      acc[j] = __builtin_amdgcn_mfma_f32_16x16x32_bf16(afrag[kk], b, acc[j], 0, 0, 0);
    }
  }
  __syncthreads();

  // ---- stage Wphi over the same region
#pragma unroll
  for (int p = 0; p < 8; ++p) {
    int c = p * 256 + tid;
    int row = c >> 4, slot = c & 15;
    *(uint4*)(bsm + row * 128 + ((slot ^ (row & 7)) * 8)) = *(const uint4*)(Wphi + c * 8);
  }
  __syncthreads();
#pragma unroll
  for (int kk = 0; kk < 4; ++kk) {
#pragma unroll
    for (int j = 0; j < 8; ++j) {
      short8 b = *(const short8*)(bsm + (j * 16 + l15) * 128 + (((kk * 4 + quad) ^ rsw) * 8));
      acc[j] = __builtin_amdgcn_mfma_f32_16x16x32_bf16(sfrag[kk], b, acc[j], 0, 0, 0);
    }
  }
  __syncthreads();   // all B reads done; bsm now reusable as transpose scratch

  const int isf = *flag;
  const bool valid = arow < Mvalid;
  float* wbuf = (float*)bsm + wid * 2 * CH_SZ;   // per-wave ping-pong, same-wave only
#pragma unroll
  for (int kk = 0; kk < 4; ++kk) {
    float* buf = wbuf + (kk & 1) * CH_SZ;
#pragma unroll
    for (int jj = 0; jj < 2; ++jj) {
#pragma unroll
      for (int r = 0; r < 4; ++r)
        buf[(quad * 4 + r) * CH_P + jj * 16 + l15] = acc[2 * kk + jj][r];
    }
    const int col0 = kk * 32 + quad * 8;
    const float* ap = &buf[l15 * CH_P + quad * 8];
    float4 s0 = *(const float4*)ap;
    float4 s1 = *(const float4*)(ap + 4);
    float4 b0 = *(const float4*)&bias_f[col0];
    float4 b1 = *(const float4*)&bias_f[col0 + 4];
    union { short8 s; unsigned short h[8]; } xu; xu.s = afrag[kk];
    float xv[8];
    xv[0] = bf2f(xu.h[0]) + EPSILON * tanh_fast(s0.x + b0.x);
    xv[1] = bf2f(xu.h[1]) + EPSILON * tanh_fast(s0.y + b0.y);
    xv[2] = bf2f(xu.h[2]) + EPSILON * tanh_fast(s0.z + b0.z);
    xv[3] = bf2f(xu.h[3]) + EPSILON * tanh_fast(s0.w + b0.w);
    xv[4] = bf2f(xu.h[4]) + EPSILON * tanh_fast(s1.x + b1.x);
    xv[5] = bf2f(xu.h[5]) + EPSILON * tanh_fast(s1.y + b1.y);
    xv[6] = bf2f(xu.h[6]) + EPSILON * tanh_fast(s1.z + b1.z);
    xv[7] = bf2f(xu.h[7]) + EPSILON * tanh_fast(s1.w + b1.w);
    uint4 pk;
    pk.x = f2_to_bfx2(xv[0], xv[1]); pk.y = f2_to_bfx2(xv[2], xv[3]);
    pk.z = f2_to_bfx2(xv[4], xv[5]); pk.w = f2_to_bfx2(xv[6], xv[7]);
    if (valid) {
      if (!outb) {
        // not the last iteration: persist bf16 state + fp8 z for next agg
        *(uint4*)(xb + abase + kk * 32) = pk;
        if (znext) {
          uint2 zk;
          zk.x = fp8x4_enc(xv[0] * dva, xv[1] * dva, xv[2] * dva, xv[3] * dva);
          zk.y = fp8x4_enc(xv[4] * dva, xv[5] * dva, xv[6] * dva, xv[7] * dva);
          *(uint2*)(znext + abase + kk * 32) = zk;
        }
      } else {
        // last iteration: only the output matters (xb/znext never read again)
        if (isf) {
          float* op = (float*)outb + abase + kk * 32;
          *(float4*)op = make_float4(xv[0], xv[1], xv[2], xv[3]);
          *(float4*)(op + 4) = make_float4(xv[4], xv[5], xv[6], xv[7]);
        } else {
          *(uint4*)((unsigned short*)outb + abase + kk * 32) = pk;
        }
      }
    }
  }
}

// one wave per node, quad-per-edge gather over fp8 z rows (128 B/row, 8 B/lane)
// accumulators are packed floatx2 -> v_pk_add_f32 (R9 version: measured 52-53 us,
// at the L1/TA random-gather line-rate floor)
__global__ __launch_bounds__(256) void agg_kernel(
    const unsigned char* __restrict__ zf,
    const int* __restrict__ offs,
    const int* __restrict__ csr,
    const float* __restrict__ dinv,
    unsigned short* __restrict__ g,
    int N) {
  int i = blockIdx.x * 4 + (threadIdx.x >> 6);
  if (i >= N) return;
  int lane = threadIdx.x & 63;
  int sub = lane >> 4;
  int c8 = (lane & 15) * 8;    // byte offset (8 fp8 elems per lane)

  floatx2 a01 = {0.f, 0.f}, a23 = {0.f, 0.f}, a45 = {0.f, 0.f}, a67 = {0.f, 0.f};

#define ACC8F(u) { \
  a01 += fp8x2_cvt_lo((u).x); \
  a23 += fp8x2_cvt_hi((u).x); \
  a45 += fp8x2_cvt_lo((u).y); \
  a67 += fp8x2_cvt_hi((u).y); }

  int e0 = offs[i], e1 = offs[i + 1];
  int e = e0 + sub;
  for (; e + 4 < e1; e += 8) {
    int s0 = csr[e];
    int s1 = csr[e + 4];
    uint2 u0 = *(const uint2*)(zf + (size_t)s0 * 128 + c8);
    uint2 u1 = *(const uint2*)(zf + (size_t)s1 * 128 + c8);
    ACC8F(u0); ACC8F(u1);
  }
  if (e < e1) {
    int s0 = csr[e];
    uint2 u0 = *(const uint2*)(zf + (size_t)s0 * 128 + c8);
    ACC8F(u0);
  }

  float a0 = a01.x, a1 = a01.y, a2 = a23.x, a3 = a23.y;
  float a4 = a45.x, a5 = a45.y, a6 = a67.x, a7 = a67.y;

  a0 += __shfl_xor(a0, 16, 64); a0 += __shfl_xor(a0, 32, 64);
  a1 += __shfl_xor(a1, 16, 64); a1 += __shfl_xor(a1, 32, 64);
  a2 += __shfl_xor(a2, 16, 64); a2 += __shfl_xor(a2, 32, 64);
  a3 += __shfl_xor(a3, 16, 64); a3 += __shfl_xor(a3, 32, 64);
  a4 += __shfl_xor(a4, 16, 64); a4 += __shfl_xor(a4, 32, 64);
  a5 += __shfl_xor(a5, 16, 64); a5 += __shfl_xor(a5, 32, 64);
  a6 += __shfl_xor(a6, 16, 64); a6 += __shfl_xor(a6, 32, 64);
  a7 += __shfl_xor(a7, 16, 64); a7 += __shfl_xor(a7, 32, 64);

  if (sub == 0) {
    uint2 su = *(const uint2*)(zf + (size_t)i * 128 + c8);
    floatx2 s01 = fp8x2_cvt_lo(su.x), s23 = fp8x2_cvt_hi(su.x);
    floatx2 s45 = fp8x2_cvt_lo(su.y), s67 = fp8x2_cvt_hi(su.y);
    a0 += s01.x; a1 += s01.y; a2 += s23.x; a3 += s23.y;
    a4 += s45.x; a5 += s45.y; a6 += s67.x; a7 += s67.y;
    float dv = dinv[i];
    uint4 o;
    o.x = f2_to_bfx2(a0 * dv, a1 * dv);
    o.y = f2_to_bfx2(a2 * dv, a3 * dv);
    o.z = f2_to_bfx2(a4 * dv, a5 * dv);
    o.w = f2_to_bfx2(a6 * dv, a7 * dv);
    *(uint4*)(g + (size_t)i * 128 + c8) = o;   // g is bf16: c8 = ushort index here
  }
#undef ACC8F
}

// ------------------------------------------------------------- launch

extern "C" void kernel_launch(void* const* d_in, const int* in_sizes, int n_in,
                              void* d_out, int out_size, void* d_ws, size_t ws_size,
                              hipStream_t stream) {
  const void* x_in = d_in[0];
  const int* ei = (const int*)d_in[1];
  const void* W = d_in[2];
  const void* Wphi = d_in[3];
  const void* bias = d_in[4];

  const int N = in_sizes[0] / 128;
  const int E = in_sizes[1] / 2;
  const int NP = ((N + 63) / 64) * 64;
  const int* src = ei;
  const int* dst = ei + E;
  const int NB = (N + 511) >> BSHIFT;
  const int EB = (E + 4095) / 4096;

  size_t off = 0;
  auto place = [&](size_t bytes) { size_t r = off; off = (off + bytes + 255) & ~(size_t)255; return r; };
  size_t o_xb   = place((size_t)NP * 128 * 2);
  size_t o_z    = place((size_t)NP * 128);       // fp8: 1 B/elem
  size_t o_g    = place((size_t)NP * 128 * 2);
  size_t o_Am   = place(128 * 128 * 2);
  size_t o_Wb   = place(128 * 128 * 2);
  size_t o_bf   = place(128 * 4);
  size_t o_flag = place(4);
  size_t o_dinv = place((size_t)(NB * 512 + 64) * 4);
  size_t o_offs = place((size_t)(N + 1) * 4);
  size_t o_gcnt = place((size_t)NB * 4);
  size_t o_gofs = place((size_t)(NB + 1) * 4);
  size_t o_gcur = place((size_t)NB * 4);
  size_t o_bprs = place((size_t)E * 4);          // packed uint32 per edge
  size_t o_csr  = place((size_t)E * 4);
  if (off > ws_size || in_sizes[0] % 128 != 0 || out_size != N * 128 || n_in < 5 ||
      N > (1 << 23)) {
    fill_kernel<<<(out_size * 2 + 255) / 256, 256, 0, stream>>>(
        (unsigned short*)d_out, out_size, (unsigned short)0x3F80);
    return;
  }
  char* basep = (char*)d_ws;
  unsigned short* xb = (unsigned short*)(basep + o_xb);
  unsigned char* zf  = (unsigned char*)(basep + o_z);
  unsigned short* g  = (unsigned short*)(basep + o_g);
  unsigned short* Am = (unsigned short*)(basep + o_Am);
  unsigned short* Wb = (unsigned short*)(basep + o_Wb);
  float* bias_f = (float*)(basep + o_bf);
  int* flag   = (int*)(basep + o_flag);
  float* dinv = (float*)(basep + o_dinv);
  int* offs   = (int*)(basep + o_offs);
  int* gcnt   = (int*)(basep + o_gcnt);
  int* gofs   = (int*)(basep + o_gofs);
  int* gcur   = (int*)(basep + o_gcur);
  unsigned int* bpairs = (unsigned int*)(basep + o_bprs);
  int* csr    = (int*)(basep + o_csr);

  hipMemsetAsync(gcnt, 0, (size_t)NB * 4, stream);
  detect_kernel<<<1, 256, 0, stream>>>((const unsigned int*)x_in, flag);
  prep_kernel<<<(128 * 128 + 255) / 256, 256, 0, stream>>>(W, Wphi, bias, flag, Am, Wb, bias_f);
  init_x_kernel<<<(NP * 16 + 255) / 256, 256, 0, stream>>>(x_in, flag, xb, N, NP);
  bcount_kernel<<<EB, 256, 0, stream>>>(dst, gcnt, E, NB);
  bscan_kernel<<<1, 256, 0, stream>>>(gcnt, gofs, gcur, NB, E);
  bscatter_kernel<<<EB, 256, 0, stream>>>(src, dst, gcur, bpairs, E, NB);
  bfinal_kernel<<<NB, 256, 0, stream>>>(bpairs, gofs, offs, dinv, csr, N, NP, E);

  const int gblocks = NP / 64;
  scale_kernel<<<(NP * 16 + 255) / 256, 256, 0, stream>>>(xb, dinv, zf, NP * 16);
  for (int t = 0; t < NUM_ITERS; ++t) {
    agg_kernel<<<(N + 3) / 4, 256, 0, stream>>>(zf, offs, csr, dinv, g, N);
    void* outp = (t == NUM_ITERS - 1) ? d_out : nullptr;
    unsigned char* znext = (t == NUM_ITERS - 1) ? nullptr : zf;
    fused_kernel<<<gblocks, 256, 0, stream>>>(xb, Am, Wb, dinv, g, bias_f,
                                              outp, znext, flag, N);
  }
}